// Round 3
// baseline (3239.181 us; speedup 1.0000x reference)
//
#include <hip/hip_runtime.h>

// ---------------------------------------------------------------------------
// Round-8: fused 48-layer biLSTM, phase-A overlap + shorter recurrence chain.
//
//  - Recurrence waves: wave 0 = fwd (SIMD 0), wave 5 = bwd (SIMD 1).
//  - Phase B split at step 192. Rows 64..191 of the NEXT layer's gates are
//    computable after step 191 (row t needs fwd>=t and bwd<=t, i.e. step
//    >= max(t,255-t)); waves {2,3,6,7} (SIMDs 2/3 only, so the recurrence
//    SIMDs stay uncontended) compute them under the last 64 steps. Remaining
//    rows 0..63 & 192..255 are done by all 8 waves after phase B.
//  - Gate pre-activations are stored PRE-SCALED by s_row (exp2-ready):
//    sigmoid rows * -1/ln2*... (-1.442695), tanh rows * 2/ln2 (2.885390).
//    Cell state kept pre-scaled (c_s = 2.885390*c) by folding the factor
//    into the tanh-gate's output constants (m_=-5.7708, b_=2.88539).
//    Saves 2 muls on the per-step dependent chain.
//  - whh double-buffered in registers across layers (no vmcnt stall at
//    phase-B entry). s_setprio(1) on recurrence waves during the overlap.
//  - Only x1 (L=23) and h2 (L=47) go to global, compact (t*48+n)*32 layout.
// ---------------------------------------------------------------------------

template <int SEL>
__device__ __forceinline__ float quad_bcast(float v) {
  return __int_as_float(__builtin_amdgcn_update_dpp(
      0, __float_as_int(v), SEL * 0x55, 0xF, 0xF, true));
}

__global__ __launch_bounds__(512) void lstm_fused(
    const float* __restrict__ x, const float* __restrict__ W_ih0_1,
    const float* __restrict__ W_ih_1, const float* __restrict__ W_hh_1,
    const float* __restrict__ b_ih_1, const float* __restrict__ b_hh_1,
    const float* __restrict__ W_ih_2, const float* __restrict__ W_hh_2,
    const float* __restrict__ b_ih_2, const float* __restrict__ b_hh_2,
    float* __restrict__ x1out, float* __restrict__ h2out) {
  __shared__ float xgF[256 * 64];  // 64 KB, fwd direction
  __shared__ float xgB[256 * 64];  // 64 KB, bwd direction

  const int tid = threadIdx.x;
  const int lane = tid & 63;
  const int w = tid >> 6;     // 0..7
  const int np = blockIdx.x;  // 0..47
  const int nglob = 48 + np;  // stack-1 chain index

  const bool rec = (w == 0) || (w == 5);
  const int d = (w == 5) ? 1 : 0;  // direction for recurrence waves

  // phase-A row scale (row index == lane): tanh rows are 32..47 (g==2)
  const float srowA =
      ((lane >> 4) == 2) ? 2.885390082f : -1.442695041f;

  // ---- layer-0 init (in_sz = 1), gates pre-scaled ----
  {
    const int dd = w >> 2;
    const int wv = w & 3;
    float* xg = dd ? xgB : xgF;
    const float bias =
        (b_ih_1[dd * 64 + lane] + b_hh_1[dd * 64 + lane]) * srowA;
    const float wih0 = W_ih0_1[dd * 64 + lane] * srowA;
    const int xvb = __float_as_int(x[(size_t)(wv * 64 + lane) * 96 + nglob]);
    for (int ti = 0; ti < 64; ++ti) {
      const float xs = __int_as_float(__builtin_amdgcn_readlane(xvb, ti));
      xg[(wv * 64 + ti) * 64 + lane] = fmaf(wih0, xs, bias);
    }
  }

  // ---- recurrence-wave persistent state: whh register double-buffer ----
  int jj = 0, g = 0, r = 0;
  float s_ = 0.f, m_ = 0.f, b_ = 0.f;
  float whn[16];
  if (rec) {
    jj = lane >> 2;
    g = lane & 3;
    r = g * 16 + jj;
    s_ = (g == 2) ? 2.885390082f : -1.442695041f;
    // tanh rows output 2.885390*tanh (keeps c pre-scaled); sigmoid plain.
    m_ = (g == 2) ? -5.770780164f : 1.0f;
    b_ = (g == 2) ? 2.885390082f : 0.0f;
    const float* W0 = W_hh_1 + (size_t)d * 1024 + (size_t)r * 16;
#pragma unroll
    for (int k = 0; k < 16; ++k) whn[k] = W0[k];
  }
  __syncthreads();

  for (int L = 0; L < 48; ++L) {
    // ---- loop top: whc = s_*whn (no load stall); prefetch next whh ----
    float whc[16];
    if (rec) {
#pragma unroll
      for (int k = 0; k < 16; ++k) whc[k] = whn[k] * s_;
      const int M = (L < 47) ? (L + 1) : 47;  // clamp (last unused)
      const float* Wn = ((M < 24) ? (W_hh_1 + (size_t)M * 2048)
                                  : (W_hh_2 + (size_t)(M - 24) * 2048)) +
                        (size_t)d * 1024 + (size_t)r * 16;
#pragma unroll
      for (int k = 0; k < 16; ++k) whn[k] = Wn[k];
    }

    // ---- prefetch phase-A weights for layer M=L+1 (all waves; raw loads,
    //      waitcnt lands at first use in phase A) ----
    float wf[32], wb[32], bf, bb;
    {
      const int M = (L < 47) ? (L + 1) : 47;
      const float* WihP;
      const float* bihP;
      const float* bhhP;
      if (M < 24) {
        WihP = W_ih_1 + (size_t)(M - 1) * 4096;
        bihP = b_ih_1 + (size_t)M * 128;
        bhhP = b_hh_1 + (size_t)M * 128;
      } else {
        WihP = W_ih_2 + (size_t)(M - 24) * 4096;
        bihP = b_ih_2 + (size_t)(M - 24) * 128;
        bhhP = b_hh_2 + (size_t)(M - 24) * 128;
      }
      bf = bihP[lane] + bhhP[lane];
      bb = bihP[64 + lane] + bhhP[64 + lane];
      const float4* pf =
          reinterpret_cast<const float4*>(WihP + (size_t)lane * 32);
      const float4* pb =
          reinterpret_cast<const float4*>(WihP + 2048 + (size_t)lane * 32);
#pragma unroll
      for (int q = 0; q < 8; ++q) {
        const float4 a = pf[q];
        wf[4 * q + 0] = a.x;
        wf[4 * q + 1] = a.y;
        wf[4 * q + 2] = a.z;
        wf[4 * q + 3] = a.w;
        const float4 b = pb[q];
        wb[4 * q + 0] = b.x;
        wb[4 * q + 1] = b.y;
        wb[4 * q + 2] = b.z;
        wb[4 * q + 3] = b.w;
      }
    }

    // ---- phase-A row processor (gates of layer L+1, pre-scaled) ----
    auto phaseA_rows = [&](int t0, int cnt) {
      float4 nf[4], nb[4];
      {
        const float4* qf = reinterpret_cast<const float4*>(&xgF[t0 * 64]);
        const float4* qb = reinterpret_cast<const float4*>(&xgB[t0 * 64]);
#pragma unroll
        for (int q = 0; q < 4; ++q) {
          nf[q] = qf[q];
          nb[q] = qb[q];
        }
      }
      for (int i = 0; i < cnt; ++i) {
        const int t = t0 + i;
        float xv[32];
#pragma unroll
        for (int q = 0; q < 4; ++q) {
          const float4 a = nf[q];
          xv[4 * q + 0] = a.x;
          xv[4 * q + 1] = a.y;
          xv[4 * q + 2] = a.z;
          xv[4 * q + 3] = a.w;
          const float4 b = nb[q];
          xv[16 + 4 * q + 0] = b.x;
          xv[16 + 4 * q + 1] = b.y;
          xv[16 + 4 * q + 2] = b.z;
          xv[16 + 4 * q + 3] = b.w;
        }
        if (i + 1 < cnt) {  // prefetch next row under the FMAs
          const float4* qf =
              reinterpret_cast<const float4*>(&xgF[(t + 1) * 64]);
          const float4* qb =
              reinterpret_cast<const float4*>(&xgB[(t + 1) * 64]);
#pragma unroll
          for (int q = 0; q < 4; ++q) {
            nf[q] = qf[q];
            nb[q] = qb[q];
          }
        }
        float f0 = bf, f1 = 0.f, f2 = 0.f, f3 = 0.f;
        float g0 = bb, g1 = 0.f, g2 = 0.f, g3 = 0.f;
#pragma unroll
        for (int k = 0; k < 32; k += 4) {
          f0 = fmaf(wf[k + 0], xv[k + 0], f0);
          f1 = fmaf(wf[k + 1], xv[k + 1], f1);
          f2 = fmaf(wf[k + 2], xv[k + 2], f2);
          f3 = fmaf(wf[k + 3], xv[k + 3], f3);
          g0 = fmaf(wb[k + 0], xv[k + 0], g0);
          g1 = fmaf(wb[k + 1], xv[k + 1], g1);
          g2 = fmaf(wb[k + 2], xv[k + 2], g2);
          g3 = fmaf(wb[k + 3], xv[k + 3], g3);
        }
        xgF[t * 64 + lane] = ((f0 + f1) + (f2 + f3)) * srowA;
        xgB[t * 64 + lane] = ((g0 + g1) + (g2 + g3)) * srowA;
      }
    };

    // ---- phase B state + step runner ----
    float hs[16];
    float c = 0.f;
    int t = d ? 255 : 0;
    const int dt = d ? -1 : 1;
    float cur0 = 0.f, cur1 = 0.f;
    float* xg = d ? xgB : xgF;

#define LSTM_STEP(CUR, TT)                                                  \
  {                                                                         \
    float a0 = (CUR), a1 = 0.f, a2 = 0.f, a3 = 0.f;                         \
    _Pragma("unroll") for (int k = 0; k < 16; k += 4) {                     \
      a0 = fmaf(whc[k + 0], hs[k + 0], a0);                                 \
      a1 = fmaf(whc[k + 1], hs[k + 1], a1);                                 \
      a2 = fmaf(whc[k + 2], hs[k + 2], a2);                                 \
      a3 = fmaf(whc[k + 3], hs[k + 3], a3);                                 \
    }                                                                       \
    const float gv = (a0 + a1) + (a2 + a3);                                 \
    const float e = __builtin_amdgcn_exp2f(gv);                             \
    const float v = fmaf(m_, __builtin_amdgcn_rcpf(1.0f + e), b_);          \
    const float si = quad_bcast<0>(v);                                      \
    const float sf = quad_bcast<1>(v);                                      \
    const float tg = quad_bcast<2>(v); /* = 2.88539*tanh */                 \
    const float so = quad_bcast<3>(v);                                      \
    c = fmaf(sf, c, si * tg); /* c pre-scaled by 2.88539 */                 \
    const float e2 = __builtin_amdgcn_exp2f(c);                             \
    const float th = fmaf(-2.0f, __builtin_amdgcn_rcpf(1.0f + e2), 1.0f);   \
    const float h = so * th;                                                \
    xg[(TT)*64 + r] = h; /* row consumed; g==0 lanes land h[j] at [0..15] */ \
    const int hb = __float_as_int(h);                                       \
    _Pragma("unroll") for (int k = 0; k < 16; ++k) hs[k] =                  \
        __int_as_float(__builtin_amdgcn_readlane(hb, 4 * k));               \
  }

    auto run_steps = [&](int nsteps) {
      for (int tt = 0; tt < nsteps; tt += 2) {
        const float nx0 = xg[((t + 2 * dt) & 255) * 64 + r];
        LSTM_STEP(cur0, t)
        const float nx1 = xg[((t + 3 * dt) & 255) * 64 + r];
        LSTM_STEP(cur1, t + dt)
        cur0 = nx0;
        cur1 = nx1;
        t += 2 * dt;
      }
    };

    // ---- phase B part 1: steps 0..191 (other waves sleep at B1) ----
    if (rec) {
#pragma unroll
      for (int k = 0; k < 16; ++k) hs[k] = 0.f;
      cur0 = xg[t * 64 + r];
      cur1 = xg[(t + dt) * 64 + r];
      run_steps(192);
    }
    __syncthreads();  // B1

    // ---- phase B part 2 (steps 192..255) || overlap phase A rows 64..191
    //      (waves 2,3,6,7 on SIMDs 2/3 — recurrence SIMDs uncontended) ----
    if (rec) {
      __builtin_amdgcn_s_setprio(1);
      run_steps(64);
      __builtin_amdgcn_s_setprio(0);
    } else if (w == 2 || w == 3 || w == 6 || w == 7) {
      if (L != 23 && L != 47) {
        const int widx = ((w >> 2) << 1) | (w & 1);  // 2,3,6,7 -> 0..3
        phaseA_rows(64 + widx * 32, 32);
      }
    }
#undef LSTM_STEP
    __syncthreads();  // B2

    // ---- write-outs: x1 after stack 1, h2 at the end ----
    if (L == 23 || L == 47) {
      float* dst = (L == 23) ? x1out : h2out;
#pragma unroll
      for (int p = 0; p < 4; ++p) {
        const int gi = p * 512 + tid;  // 0..2047 float4 chunks
        const int tt = gi >> 3;
        const int cc = gi & 7;  // 0-3 fwd, 4-7 bwd
        const float* src =
            (cc < 4) ? &xgF[tt * 64 + cc * 4] : &xgB[tt * 64 + (cc - 4) * 4];
        const float4 v = *reinterpret_cast<const float4*>(src);
        *reinterpret_cast<float4*>(dst + ((size_t)tt * 48 + np) * 32 +
                                   cc * 4) = v;
      }
      if (L == 47) break;
      __syncthreads();  // protect x1 reads from phase-A overwrite
      // full phase A (no overlap happened this layer): 8 waves x 32 rows
      phaseA_rows(w * 32, 32);
    } else {
      // remaining rows 0..63 & 192..255: 8 waves x 16 rows
      const int t0 = (w < 4) ? (w * 16) : (192 + (w - 4) * 16);
      phaseA_rows(t0, 16);
    }
    __syncthreads();  // B3
  }
}

// fc1: y1[b,m] = relu( sum_k (h2[b,k] + x1[b,k]) * w1[m,k] + b1[m] )
// Both h2 and x1 are compact (256,1536).
__global__ __launch_bounds__(256) void fc1_kernel(
    const float* __restrict__ h2, const float* __restrict__ x1b,
    const float* __restrict__ w1, const float* __restrict__ b1,
    float* __restrict__ y1) {
  __shared__ float Zs[16][68];
  __shared__ float Ws[16][68];
  const int tid = threadIdx.x;
  const int m0 = blockIdx.x * 64;
  const int b0 = blockIdx.y * 64;
  const int rr = tid >> 2;
  const int c4 = (tid & 3) * 4;
  const int tx = tid & 15, ty = tid >> 4;

  float acc[4][4];
#pragma unroll
  for (int i = 0; i < 4; ++i)
#pragma unroll
    for (int jj = 0; jj < 4; ++jj) acc[i][jj] = 0.f;

  const bool wvalid = (m0 + rr) < 1000;
  const float* zr = h2 + (size_t)(b0 + rr) * 1536 + c4;
  const float* zr2 = x1b + (size_t)(b0 + rr) * 1536 + c4;
  const float* wr = w1 + (size_t)(m0 + rr) * 1536 + c4;

  float4 za = *reinterpret_cast<const float4*>(zr);
  float4 zb = *reinterpret_cast<const float4*>(zr2);
  float4 wv = wvalid ? *reinterpret_cast<const float4*>(wr)
                     : make_float4(0.f, 0.f, 0.f, 0.f);

  for (int k0 = 0; k0 < 1536; k0 += 16) {
    Zs[c4 + 0][rr] = za.x + zb.x;
    Zs[c4 + 1][rr] = za.y + zb.y;
    Zs[c4 + 2][rr] = za.z + zb.z;
    Zs[c4 + 3][rr] = za.w + zb.w;
    Ws[c4 + 0][rr] = wv.x;
    Ws[c4 + 1][rr] = wv.y;
    Ws[c4 + 2][rr] = wv.z;
    Ws[c4 + 3][rr] = wv.w;
    if (k0 + 16 < 1536) {
      za = *reinterpret_cast<const float4*>(zr + k0 + 16);
      zb = *reinterpret_cast<const float4*>(zr2 + k0 + 16);
      if (wvalid) wv = *reinterpret_cast<const float4*>(wr + k0 + 16);
    }
    __syncthreads();
#pragma unroll
    for (int kk = 0; kk < 16; ++kk) {
      const float4 av = *reinterpret_cast<const float4*>(&Zs[kk][ty * 4]);
      const float4 bv = *reinterpret_cast<const float4*>(&Ws[kk][tx * 4]);
      const float a_[4] = {av.x, av.y, av.z, av.w};
      const float b_[4] = {bv.x, bv.y, bv.z, bv.w};
#pragma unroll
      for (int i = 0; i < 4; ++i)
#pragma unroll
        for (int jj = 0; jj < 4; ++jj)
          acc[i][jj] = fmaf(a_[i], b_[jj], acc[i][jj]);
    }
    __syncthreads();
  }
#pragma unroll
  for (int i = 0; i < 4; ++i) {
    const int b = b0 + ty * 4 + i;
#pragma unroll
    for (int jj = 0; jj < 4; ++jj) {
      const int m = m0 + tx * 4 + jj;
      if (m < 1000) {
        float vo = acc[i][jj] + b1[m];
        y1[(size_t)b * 1000 + m] = vo > 0.f ? vo : 0.f;
      }
    }
  }
}

// fc2: out[b,p] = sum_m y1[b,m]*w2[p,m] + b2[p], p<48; FP32 store.
__global__ __launch_bounds__(64) void fc2_kernel(
    const float* __restrict__ y1, const float* __restrict__ w2,
    const float* __restrict__ b2, float* __restrict__ out) {
  __shared__ float ys[1000];
  const int b = blockIdx.x;
  for (int k = threadIdx.x; k < 1000; k += 64) ys[k] = y1[(size_t)b * 1000 + k];
  __syncthreads();
  const int p = threadIdx.x;
  if (p < 48) {
    float a0 = b2[p], a1 = 0.f, a2 = 0.f, a3 = 0.f;
    const float* wr = w2 + (size_t)p * 1000;
    for (int k = 0; k < 1000; k += 4) {
      const float4 wv = *reinterpret_cast<const float4*>(wr + k);
      a0 = fmaf(ys[k + 0], wv.x, a0);
      a1 = fmaf(ys[k + 1], wv.y, a1);
      a2 = fmaf(ys[k + 2], wv.z, a2);
      a3 = fmaf(ys[k + 3], wv.w, a3);
    }
    out[(size_t)b * 48 + p] = (a0 + a1) + (a2 + a3);
  }
}

extern "C" void kernel_launch(void* const* d_in, const int* in_sizes, int n_in,
                              void* d_out, int out_size, void* d_ws,
                              size_t ws_size, hipStream_t stream) {
  const float* x = (const float*)d_in[0];
  const float* W_ih0_1 = (const float*)d_in[1];
  const float* W_ih_1 = (const float*)d_in[2];
  const float* W_hh_1 = (const float*)d_in[3];
  const float* b_ih_1 = (const float*)d_in[4];
  const float* b_hh_1 = (const float*)d_in[5];
  const float* W_ih_2 = (const float*)d_in[6];
  const float* W_hh_2 = (const float*)d_in[7];
  const float* b_ih_2 = (const float*)d_in[8];
  const float* b_hh_2 = (const float*)d_in[9];
  const float* fc1_w = (const float*)d_in[10];
  const float* fc1_b = (const float*)d_in[11];
  const float* fc2_w = (const float*)d_in[12];
  const float* fc2_b = (const float*)d_in[13];

  float* ws = (float*)d_ws;
  float* x1b = ws;           // 393216 floats (256*48*32)
  float* h2b = ws + 393216;  // 393216 floats
  float* y1 = ws + 786432;   // 256000 floats

  lstm_fused<<<48, 512, 0, stream>>>(x, W_ih0_1, W_ih_1, W_hh_1, b_ih_1,
                                     b_hh_1, W_ih_2, W_hh_2, b_ih_2, b_hh_2,
                                     x1b, h2b);
  fc1_kernel<<<dim3(16, 4), 256, 0, stream>>>(h2b, x1b, fc1_w, fc1_b, y1);
  fc2_kernel<<<256, 64, 0, stream>>>(y1, fc2_w, fc2_b, (float*)d_out);
}

// Round 4
// 2422.331 us; speedup vs baseline: 1.3372x; 1.3372x over previous
//
#include <hip/hip_runtime.h>

// ---------------------------------------------------------------------------
// Round-9: fused 48-layer biLSTM — spill elimination + clean overlap.
//
// Round-8 post-mortem: WRITE_SIZE 40-82MB/dispatch = register spills
// (launch_bounds(512) capped VGPR at 128; we run 1 block/CU => can afford
// 256). Pre-scaled-gate numerics also degraded absmax 500x. Both reverted.
//
//  - __launch_bounds__(512, 2): 256 VGPRs/wave, no occupancy loss (1 block/CU
//    due to 128 KB LDS anyway). Kills all spill traffic.
//  - Numerics = round-7 proven form (absmax ~6e-5).
//  - Recurrence: wave 0 = fwd (SIMD 0), wave 5 = bwd (SIMD 1); these waves
//    NEVER load phase-A weights (lean live set in the serial loop).
//  - Phase-B split at step 192: rows 64..191 of next layer's gates are ready
//    after step 191 (row t needs fwd>=t, bwd>=255-t); waves {2,3,6,7}
//    (SIMDs 2/3 only) compute them under the last 64 steps. Remaining rows
//    0..63 & 192..255 by the 6 non-rec waves after phase B.
//  - whh register double-buffer across layers (no load stall at B entry).
//  - Only x1 (L=23) and h2 (L=47) to global, compact (t*48+n)*32 layout.
// ---------------------------------------------------------------------------

template <int SEL>
__device__ __forceinline__ float quad_bcast(float v) {
  return __int_as_float(__builtin_amdgcn_update_dpp(
      0, __float_as_int(v), SEL * 0x55, 0xF, 0xF, true));
}

__global__ __launch_bounds__(512, 2) void lstm_fused(
    const float* __restrict__ x, const float* __restrict__ W_ih0_1,
    const float* __restrict__ W_ih_1, const float* __restrict__ W_hh_1,
    const float* __restrict__ b_ih_1, const float* __restrict__ b_hh_1,
    const float* __restrict__ W_ih_2, const float* __restrict__ W_hh_2,
    const float* __restrict__ b_ih_2, const float* __restrict__ b_hh_2,
    float* __restrict__ x1out, float* __restrict__ h2out) {
  __shared__ float xgF[256 * 64];  // 64 KB, fwd direction
  __shared__ float xgB[256 * 64];  // 64 KB, bwd direction

  const int tid = threadIdx.x;
  const int lane = tid & 63;
  const int w = tid >> 6;     // 0..7
  const int np = blockIdx.x;  // 0..47
  const int nglob = 48 + np;  // stack-1 chain index

  const bool rec = (w == 0) || (w == 5);
  const int d = (w == 5) ? 1 : 0;
  // overlap waves: {2,3,6,7} -> SIMDs 2,3 (rec waves own SIMDs 0,1)
  const bool ovl = (w == 2) || (w == 3) || (w == 6) || (w == 7);
  const int ovlIdx = (w & 1) | ((w >> 2) << 1);        // {2,3,6,7}->0..3
  const int widx = (w < 5) ? (w - 1) : (w - 2);        // {1..4,6,7}->0..5

  // ---- layer-0 init (in_sz = 1) ----
  {
    const int dd = w >> 2;
    const int wv = w & 3;
    float* xg = dd ? xgB : xgF;
    const float bias = b_ih_1[dd * 64 + lane] + b_hh_1[dd * 64 + lane];
    const float wih0 = W_ih0_1[dd * 64 + lane];
    const int xvb = __float_as_int(x[(size_t)(wv * 64 + lane) * 96 + nglob]);
    for (int ti = 0; ti < 64; ++ti) {
      const float xs = __int_as_float(__builtin_amdgcn_readlane(xvb, ti));
      xg[(wv * 64 + ti) * 64 + lane] = fmaf(wih0, xs, bias);
    }
  }

  // ---- recurrence-wave persistent state ----
  int g = 0, r = 0;
  float s_ = 0.f, m_ = 0.f, b_ = 0.f;
  float whn[16];
  if (rec) {
    g = lane & 3;
    r = g * 16 + (lane >> 2);
    s_ = (g == 2) ? 2.885390082f : -1.442695041f;
    m_ = (g == 2) ? -2.0f : 1.0f;
    b_ = (g == 2) ? 1.0f : 0.0f;
    const float* W0 = W_hh_1 + (size_t)d * 1024 + (size_t)r * 16;
#pragma unroll
    for (int k = 0; k < 16; ++k) whn[k] = W0[k];
  }
  __syncthreads();

  for (int L = 0; L < 48; ++L) {
    // ---- rec: current whh from double-buffer; prefetch next layer's ----
    float whh[16];
    if (rec) {
#pragma unroll
      for (int k = 0; k < 16; ++k) whh[k] = whn[k];
      const int M = (L < 47) ? (L + 1) : 47;  // clamp (last unused)
      const float* Wn = ((M < 24) ? (W_hh_1 + (size_t)M * 2048)
                                  : (W_hh_2 + (size_t)(M - 24) * 2048)) +
                        (size_t)d * 1024 + (size_t)r * 16;
#pragma unroll
      for (int k = 0; k < 16; ++k) whn[k] = Wn[k];
    }

    // ---- non-rec: prefetch phase-A weights for layer M=L+1 (raw loads;
    //      waitcnt lands at first use) ----
    float wf[32], wb[32], bf = 0.f, bb = 0.f;
    if (!rec) {
      const int M = (L < 47) ? (L + 1) : 47;
      const float* WihP;
      const float* bihP;
      const float* bhhP;
      if (M < 24) {
        WihP = W_ih_1 + (size_t)(M - 1) * 4096;
        bihP = b_ih_1 + (size_t)M * 128;
        bhhP = b_hh_1 + (size_t)M * 128;
      } else {
        WihP = W_ih_2 + (size_t)(M - 24) * 4096;
        bihP = b_ih_2 + (size_t)(M - 24) * 128;
        bhhP = b_hh_2 + (size_t)(M - 24) * 128;
      }
      bf = bihP[lane] + bhhP[lane];
      bb = bihP[64 + lane] + bhhP[64 + lane];
      const float4* pf =
          reinterpret_cast<const float4*>(WihP + (size_t)lane * 32);
      const float4* pb =
          reinterpret_cast<const float4*>(WihP + 2048 + (size_t)lane * 32);
#pragma unroll
      for (int q = 0; q < 8; ++q) {
        const float4 a = pf[q];
        wf[4 * q + 0] = a.x;
        wf[4 * q + 1] = a.y;
        wf[4 * q + 2] = a.z;
        wf[4 * q + 3] = a.w;
        const float4 b = pb[q];
        wb[4 * q + 0] = b.x;
        wb[4 * q + 1] = b.y;
        wb[4 * q + 2] = b.z;
        wb[4 * q + 3] = b.w;
      }
    }

    // ---- phase-A helpers (only called on non-rec waves) ----
    auto compute_row = [&](int t, const float4 (&F)[4], const float4 (&Bv)[4]) {
      float f0 = bf, f1 = 0.f, f2 = 0.f, f3 = 0.f;
      float g0 = bb, g1 = 0.f, g2 = 0.f, g3 = 0.f;
#pragma unroll
      for (int q = 0; q < 4; ++q) {
        const float4 a = F[q];
        f0 = fmaf(wf[4 * q + 0], a.x, f0);
        f1 = fmaf(wf[4 * q + 1], a.y, f1);
        f2 = fmaf(wf[4 * q + 2], a.z, f2);
        f3 = fmaf(wf[4 * q + 3], a.w, f3);
        g0 = fmaf(wb[4 * q + 0], a.x, g0);
        g1 = fmaf(wb[4 * q + 1], a.y, g1);
        g2 = fmaf(wb[4 * q + 2], a.z, g2);
        g3 = fmaf(wb[4 * q + 3], a.w, g3);
        const float4 b = Bv[q];
        f0 = fmaf(wf[16 + 4 * q + 0], b.x, f0);
        f1 = fmaf(wf[16 + 4 * q + 1], b.y, f1);
        f2 = fmaf(wf[16 + 4 * q + 2], b.z, f2);
        f3 = fmaf(wf[16 + 4 * q + 3], b.w, f3);
        g0 = fmaf(wb[16 + 4 * q + 0], b.x, g0);
        g1 = fmaf(wb[16 + 4 * q + 1], b.y, g1);
        g2 = fmaf(wb[16 + 4 * q + 2], b.z, g2);
        g3 = fmaf(wb[16 + 4 * q + 3], b.w, g3);
      }
      xgF[t * 64 + lane] = (f0 + f1) + (f2 + f3);
      xgB[t * 64 + lane] = (g0 + g1) + (g2 + g3);
    };

    auto phaseA_rows = [&](int t0, int cnt) {  // cnt even, 2-row pipeline
      float4 af[4], ab4[4], nf[4], nb[4];
      {
        const float4* qf = reinterpret_cast<const float4*>(&xgF[t0 * 64]);
        const float4* qb = reinterpret_cast<const float4*>(&xgB[t0 * 64]);
#pragma unroll
        for (int q = 0; q < 4; ++q) {
          af[q] = qf[q];
          ab4[q] = qb[q];
        }
      }
      for (int i = 0; i < cnt; i += 2) {
        const int t = t0 + i;
        {  // prefetch row t+1
          const float4* qf =
              reinterpret_cast<const float4*>(&xgF[(t + 1) * 64]);
          const float4* qb =
              reinterpret_cast<const float4*>(&xgB[(t + 1) * 64]);
#pragma unroll
          for (int q = 0; q < 4; ++q) {
            nf[q] = qf[q];
            nb[q] = qb[q];
          }
        }
        compute_row(t, af, ab4);
        if (i + 2 < cnt) {  // prefetch row t+2
          const float4* qf =
              reinterpret_cast<const float4*>(&xgF[(t + 2) * 64]);
          const float4* qb =
              reinterpret_cast<const float4*>(&xgB[(t + 2) * 64]);
#pragma unroll
          for (int q = 0; q < 4; ++q) {
            af[q] = qf[q];
            ab4[q] = qb[q];
          }
        }
        compute_row(t + 1, nf, nb);
      }
    };

    // ---- phase B (round-7 numerics) ----
    float hs[16];
    float c = 0.f;
    int t = d ? 255 : 0;
    const int dt = d ? -1 : 1;
    float cur0 = 0.f, cur1 = 0.f;
    float* xg = d ? xgB : xgF;

#define LSTM_STEP(CUR, TT)                                                  \
  {                                                                         \
    float a0 = (CUR), a1 = 0.f, a2 = 0.f, a3 = 0.f;                         \
    _Pragma("unroll") for (int k = 0; k < 16; k += 4) {                     \
      a0 = fmaf(whh[k + 0], hs[k + 0], a0);                                 \
      a1 = fmaf(whh[k + 1], hs[k + 1], a1);                                 \
      a2 = fmaf(whh[k + 2], hs[k + 2], a2);                                 \
      a3 = fmaf(whh[k + 3], hs[k + 3], a3);                                 \
    }                                                                       \
    const float gv = (a0 + a1) + (a2 + a3);                                 \
    const float e = __builtin_amdgcn_exp2f(s_ * gv);                        \
    const float v = fmaf(m_, __builtin_amdgcn_rcpf(1.0f + e), b_);          \
    const float si = quad_bcast<0>(v);                                      \
    const float sf = quad_bcast<1>(v);                                      \
    const float tg = quad_bcast<2>(v);                                      \
    const float so = quad_bcast<3>(v);                                      \
    c = fmaf(sf, c, si * tg);                                               \
    const float e2 = __builtin_amdgcn_exp2f(2.885390082f * c);              \
    const float th = fmaf(-2.0f, __builtin_amdgcn_rcpf(1.0f + e2), 1.0f);   \
    const float h = so * th;                                                \
    xg[(TT)*64 + r] = h; /* row consumed; g==0 lanes land h[j] at [0..15] */ \
    const int hb = __float_as_int(h);                                       \
    _Pragma("unroll") for (int k = 0; k < 16; ++k) hs[k] =                  \
        __int_as_float(__builtin_amdgcn_readlane(hb, 4 * k));               \
  }

    auto run_steps = [&](int nsteps) {
      for (int tt = 0; tt < nsteps; tt += 2) {
        const float nx0 = xg[((t + 2 * dt) & 255) * 64 + r];
        LSTM_STEP(cur0, t)
        const float nx1 = xg[((t + 3 * dt) & 255) * 64 + r];
        LSTM_STEP(cur1, t + dt)
        cur0 = nx0;
        cur1 = nx1;
        t += 2 * dt;
      }
    };

    // ---- phase B part 1: steps 0..191 ----
    if (rec) {
#pragma unroll
      for (int k = 0; k < 16; ++k) hs[k] = 0.f;
      cur0 = xg[t * 64 + r];
      cur1 = xg[(t + dt) * 64 + r];
      run_steps(192);
    }
    __syncthreads();  // B1

    // ---- phase B part 2 (steps 192..255) || phase-A rows 64..191 on
    //      waves {2,3,6,7} (SIMDs 2/3; rec SIMDs uncontended) ----
    if (rec) {
      __builtin_amdgcn_s_setprio(1);
      run_steps(64);
      __builtin_amdgcn_s_setprio(0);
    } else if (ovl && L != 23 && L != 47) {
      phaseA_rows(64 + ovlIdx * 32, 32);
    }
#undef LSTM_STEP
    __syncthreads();  // B2

    // ---- write-outs + remaining phase A ----
    if (L == 23 || L == 47) {
      float* dst = (L == 23) ? x1out : h2out;
#pragma unroll
      for (int p = 0; p < 4; ++p) {
        const int gi = p * 512 + tid;  // 0..2047 float4 chunks
        const int tt = gi >> 3;
        const int cc = gi & 7;  // 0-3 fwd, 4-7 bwd
        const float* src =
            (cc < 4) ? &xgF[tt * 64 + cc * 4] : &xgB[tt * 64 + (cc - 4) * 4];
        const float4 v = *reinterpret_cast<const float4*>(src);
        *reinterpret_cast<float4*>(dst + ((size_t)tt * 48 + np) * 32 +
                                   cc * 4) = v;
      }
      if (L == 47) break;
      __syncthreads();  // protect x1 reads from phase-A overwrite
      if (!rec) {       // full phase A: 6 waves, rows {44,44,44,44,40,40}
        const int t0 = (widx < 4) ? widx * 44 : 176 + (widx - 4) * 40;
        phaseA_rows(t0, (widx < 4) ? 44 : 40);
      }
    } else {
      if (!rec) {  // remaining rows 0..63 & 192..255: 6 waves {22,22,20}x2
        const int half = widx / 3;
        const int k3 = widx - half * 3;
        phaseA_rows(half * 192 + k3 * 22, (k3 == 2) ? 20 : 22);
      }
    }
    __syncthreads();  // B3
  }
}

// fc1: y1[b,m] = relu( sum_k (h2[b,k] + x1[b,k]) * w1[m,k] + b1[m] )
// Both h2 and x1 are compact (256,1536).
__global__ __launch_bounds__(256) void fc1_kernel(
    const float* __restrict__ h2, const float* __restrict__ x1b,
    const float* __restrict__ w1, const float* __restrict__ b1,
    float* __restrict__ y1) {
  __shared__ float Zs[16][68];
  __shared__ float Ws[16][68];
  const int tid = threadIdx.x;
  const int m0 = blockIdx.x * 64;
  const int b0 = blockIdx.y * 64;
  const int rr = tid >> 2;
  const int c4 = (tid & 3) * 4;
  const int tx = tid & 15, ty = tid >> 4;

  float acc[4][4];
#pragma unroll
  for (int i = 0; i < 4; ++i)
#pragma unroll
    for (int jj = 0; jj < 4; ++jj) acc[i][jj] = 0.f;

  const bool wvalid = (m0 + rr) < 1000;
  const float* zr = h2 + (size_t)(b0 + rr) * 1536 + c4;
  const float* zr2 = x1b + (size_t)(b0 + rr) * 1536 + c4;
  const float* wr = w1 + (size_t)(m0 + rr) * 1536 + c4;

  float4 za = *reinterpret_cast<const float4*>(zr);
  float4 zb = *reinterpret_cast<const float4*>(zr2);
  float4 wv = wvalid ? *reinterpret_cast<const float4*>(wr)
                     : make_float4(0.f, 0.f, 0.f, 0.f);

  for (int k0 = 0; k0 < 1536; k0 += 16) {
    Zs[c4 + 0][rr] = za.x + zb.x;
    Zs[c4 + 1][rr] = za.y + zb.y;
    Zs[c4 + 2][rr] = za.z + zb.z;
    Zs[c4 + 3][rr] = za.w + zb.w;
    Ws[c4 + 0][rr] = wv.x;
    Ws[c4 + 1][rr] = wv.y;
    Ws[c4 + 2][rr] = wv.z;
    Ws[c4 + 3][rr] = wv.w;
    if (k0 + 16 < 1536) {
      za = *reinterpret_cast<const float4*>(zr + k0 + 16);
      zb = *reinterpret_cast<const float4*>(zr2 + k0 + 16);
      if (wvalid) wv = *reinterpret_cast<const float4*>(wr + k0 + 16);
    }
    __syncthreads();
#pragma unroll
    for (int kk = 0; kk < 16; ++kk) {
      const float4 av = *reinterpret_cast<const float4*>(&Zs[kk][ty * 4]);
      const float4 bv = *reinterpret_cast<const float4*>(&Ws[kk][tx * 4]);
      const float a_[4] = {av.x, av.y, av.z, av.w};
      const float b_[4] = {bv.x, bv.y, bv.z, bv.w};
#pragma unroll
      for (int i = 0; i < 4; ++i)
#pragma unroll
        for (int jj = 0; jj < 4; ++jj)
          acc[i][jj] = fmaf(a_[i], b_[jj], acc[i][jj]);
    }
    __syncthreads();
  }
#pragma unroll
  for (int i = 0; i < 4; ++i) {
    const int b = b0 + ty * 4 + i;
#pragma unroll
    for (int jj = 0; jj < 4; ++jj) {
      const int m = m0 + tx * 4 + jj;
      if (m < 1000) {
        float vo = acc[i][jj] + b1[m];
        y1[(size_t)b * 1000 + m] = vo > 0.f ? vo : 0.f;
      }
    }
  }
}

// fc2: out[b,p] = sum_m y1[b,m]*w2[p,m] + b2[p], p<48; FP32 store.
__global__ __launch_bounds__(64) void fc2_kernel(
    const float* __restrict__ y1, const float* __restrict__ w2,
    const float* __restrict__ b2, float* __restrict__ out) {
  __shared__ float ys[1000];
  const int b = blockIdx.x;
  for (int k = threadIdx.x; k < 1000; k += 64) ys[k] = y1[(size_t)b * 1000 + k];
  __syncthreads();
  const int p = threadIdx.x;
  if (p < 48) {
    float a0 = b2[p], a1 = 0.f, a2 = 0.f, a3 = 0.f;
    const float* wr = w2 + (size_t)p * 1000;
    for (int k = 0; k < 1000; k += 4) {
      const float4 wv = *reinterpret_cast<const float4*>(wr + k);
      a0 = fmaf(ys[k + 0], wv.x, a0);
      a1 = fmaf(ys[k + 1], wv.y, a1);
      a2 = fmaf(ys[k + 2], wv.z, a2);
      a3 = fmaf(ys[k + 3], wv.w, a3);
    }
    out[(size_t)b * 48 + p] = (a0 + a1) + (a2 + a3);
  }
}

extern "C" void kernel_launch(void* const* d_in, const int* in_sizes, int n_in,
                              void* d_out, int out_size, void* d_ws,
                              size_t ws_size, hipStream_t stream) {
  const float* x = (const float*)d_in[0];
  const float* W_ih0_1 = (const float*)d_in[1];
  const float* W_ih_1 = (const float*)d_in[2];
  const float* W_hh_1 = (const float*)d_in[3];
  const float* b_ih_1 = (const float*)d_in[4];
  const float* b_hh_1 = (const float*)d_in[5];
  const float* W_ih_2 = (const float*)d_in[6];
  const float* W_hh_2 = (const float*)d_in[7];
  const float* b_ih_2 = (const float*)d_in[8];
  const float* b_hh_2 = (const float*)d_in[9];
  const float* fc1_w = (const float*)d_in[10];
  const float* fc1_b = (const float*)d_in[11];
  const float* fc2_w = (const float*)d_in[12];
  const float* fc2_b = (const float*)d_in[13];

  float* ws = (float*)d_ws;
  float* x1b = ws;           // 393216 floats (256*48*32)
  float* h2b = ws + 393216;  // 393216 floats
  float* y1 = ws + 786432;   // 256000 floats

  lstm_fused<<<48, 512, 0, stream>>>(x, W_ih0_1, W_ih_1, W_hh_1, b_ih_1,
                                     b_hh_1, W_ih_2, W_hh_2, b_ih_2, b_hh_2,
                                     x1b, h2b);
  fc1_kernel<<<dim3(16, 4), 256, 0, stream>>>(h2b, x1b, fc1_w, fc1_b, y1);
  fc2_kernel<<<256, 64, 0, stream>>>(y1, fc2_w, fc2_b, (float*)d_out);
}